// Round 4
// baseline (936.917 us; speedup 1.0000x reference)
//
#include <hip/hip_runtime.h>
#include <stdint.h>

// Problem constants
#define Hh 32
#define Pp 128
#define Nn 128
#define Gg 8
#define Kk 4
#define CHc 256
#define Ee 2048
#define Ii 4096
#define CDd 6144
#define Mm 4096        // b*s = 2*2048
#define NCn 8
#define GNn 1024
#define NG1 10240      // gate+hbc columns (dt columns done in fp32 gemv)

using short8  = __attribute__((ext_vector_type(8))) short;
using floatx4 = __attribute__((ext_vector_type(4))) float;

__device__ __forceinline__ unsigned short f2bf(float f) {
  unsigned u = __float_as_uint(f);
  u += 0x7FFF + ((u >> 16) & 1);           // round-to-nearest-even
  return (unsigned short)(u >> 16);
}
__device__ __forceinline__ float bf2f(unsigned short s) {
  return __uint_as_float(((unsigned)s) << 16);
}
__device__ __forceinline__ void gld_lds16(void* lds, const void* g) {
  __builtin_amdgcn_global_load_lds(
      (const __attribute__((address_space(1))) void*)g,
      (__attribute__((address_space(3))) void*)lds, 16, 0, 0);
}

// ws probe: if workspace too small, expose its MB count as d_out[0]
__global__ void ws_probe(float* out, float mb) { out[0] = mb; }

// ---------------- convert fp32 -> bf16 (vectorized) ----------------
__global__ __launch_bounds__(256) void cvt_bf16(const float* __restrict__ src,
                                                unsigned short* __restrict__ dst,
                                                size_t n4) {
  size_t i = (size_t)blockIdx.x * 256 + threadIdx.x;
  if (i < n4) {
    float4 v = ((const float4*)src)[i];
    ushort4 o;
    o.x = f2bf(v.x); o.y = f2bf(v.y); o.z = f2bf(v.z); o.w = f2bf(v.w);
    ((ushort4*)dst)[i] = o;
  }
}

// ---------------- exact fp32 GEMV for dt columns + fused x->bf16 ----------------
__global__ __launch_bounds__(256) void dt_gemv(const float* __restrict__ x,
                                               const float* __restrict__ W1,
                                               float* __restrict__ dtraw,
                                               unsigned short* __restrict__ xbf) {
  int row = blockIdx.x;
  __shared__ float xs[Ee];
  for (int i = threadIdx.x; i < Ee / 4; i += 256) {
    float4 v = ((const float4*)(x + (size_t)row * Ee))[i];
    ((float4*)xs)[i] = v;
    ushort4 o;
    o.x = f2bf(v.x); o.y = f2bf(v.y); o.z = f2bf(v.z); o.w = f2bf(v.w);
    ((ushort4*)(xbf + (size_t)row * Ee))[i] = o;
  }
  __syncthreads();
  int h = threadIdx.x >> 3, seg = threadIdx.x & 7;
  const float* wr = W1 + (size_t)(NG1 + h) * Ee;
  float s = 0.f;
  for (int k = seg; k < Ee; k += 8) s = fmaf(xs[k], wr[k], s);
  s += __shfl_xor(s, 1);
  s += __shfl_xor(s, 2);
  s += __shfl_xor(s, 4);
  if (seg == 0) dtraw[(size_t)row * Hh + h] = s;
}

// ---------------- bf16 MFMA GEMM, B given as N x K (B^T pattern) ----------------
// 1-D grid with GM=16 supergroup swizzle for L2 locality.
// mode 0: plain fp32 out (pitch Nout).  mode 1: split epilogue gate(bf16)/hbc(bf16).
#define BM 128
#define BN 128
#define BK 64
__global__ __launch_bounds__(256) void gemm_bt(const unsigned short* __restrict__ A,
                                               const unsigned short* __restrict__ B,
                                               int K, int nbn, int mode,
                                               float* __restrict__ out_f,
                                               unsigned short* __restrict__ out_gate,
                                               unsigned short* __restrict__ out_hbc,
                                               int Nout) {
  __shared__ unsigned short As[BM * BK];
  __shared__ unsigned short Bs[BN * BK];
  const int tid = threadIdx.x;
  const int wid = tid >> 6, lane = tid & 63;
  const int q = lane >> 4, l16 = lane & 15;
  // supergroup decode: GM=16 m-tiles per group, m fastest within group
  const int per = nbn << 4;
  const int grp = blockIdx.x / per;
  const int rem = blockIdx.x - grp * per;
  const int mi = (grp << 4) + (rem & 15);
  const int ni = rem >> 4;
  const int m0 = mi * BM;
  const int n0 = ni * BN;
  floatx4 acc[8][2] = {};

  const int cb = tid & 192;  // wave-uniform chunk base bits (= wid*64)
  for (int k0 = 0; k0 < K; k0 += BK) {
    __syncthreads();
#pragma unroll
    for (int it = 0; it < 4; ++it) {
      int chunkbase = it * 256 + cb;
      int chunk = chunkbase + lane;
      int m = chunk >> 3, kk = (chunk & 7) << 3;
      gld_lds16(&As[chunkbase * 8], &A[(size_t)(m0 + m) * K + k0 + kk]);
      gld_lds16(&Bs[chunkbase * 8], &B[(size_t)(n0 + m) * K + k0 + kk]);
    }
    __syncthreads();
#pragma unroll
    for (int kk = 0; kk < BK; kk += 32) {
      const int ko = kk + q * 8;
      short8 af[8];
#pragma unroll
      for (int mt = 0; mt < 8; ++mt)
        af[mt] = *(const short8*)&As[(mt * 16 + l16) * BK + ko];
      short8 bf0 = *(const short8*)&Bs[(wid * 32 + l16) * BK + ko];
      short8 bf1 = *(const short8*)&Bs[(wid * 32 + 16 + l16) * BK + ko];
#pragma unroll
      for (int mt = 0; mt < 8; ++mt) {
        acc[mt][0] = __builtin_amdgcn_mfma_f32_16x16x32_bf16(af[mt], bf0, acc[mt][0], 0, 0, 0);
        acc[mt][1] = __builtin_amdgcn_mfma_f32_16x16x32_bf16(af[mt], bf1, acc[mt][1], 0, 0, 0);
      }
    }
  }
#pragma unroll
  for (int mt = 0; mt < 8; ++mt)
#pragma unroll
    for (int nt = 0; nt < 2; ++nt)
#pragma unroll
      for (int r = 0; r < 4; ++r) {
        int row = m0 + mt * 16 + q * 4 + r;
        int col = n0 + wid * 32 + nt * 16 + l16;
        float v = acc[mt][nt][r];
        if (mode == 0) {
          out_f[(size_t)row * Nout + col] = v;
        } else {
          if (col < Ii) out_gate[(size_t)row * Ii + col] = f2bf(v);
          else out_hbc[(size_t)row * CDd + (col - Ii)] = f2bf(v);
        }
      }
}

// ---------------- depthwise causal conv K=4 + bias + silu, split bf16 outputs ----------------
__global__ __launch_bounds__(256) void conv_silu(const unsigned short* __restrict__ hbc,
                                                 const float* __restrict__ cw,
                                                 const float* __restrict__ cb,
                                                 unsigned short* __restrict__ Xr,
                                                 unsigned short* __restrict__ Bb,
                                                 unsigned short* __restrict__ Cb) {
  int idx = blockIdx.x * 256 + threadIdx.x;   // over Mm*CDd/4
  int c4 = (idx % (CDd / 4)) * 4;
  int row = idx / (CDd / 4);
  int s = row & 2047;
  const unsigned short* base = hbc + (size_t)row * CDd + c4;
  ushort4 zero = {0, 0, 0, 0};
  ushort4 r0 = (s >= 3) ? *(const ushort4*)(base - (size_t)3 * CDd) : zero;
  ushort4 r1 = (s >= 2) ? *(const ushort4*)(base - (size_t)2 * CDd) : zero;
  ushort4 r2 = (s >= 1) ? *(const ushort4*)(base - (size_t)1 * CDd) : zero;
  ushort4 r3 = *(const ushort4*)base;
  float i0[4] = {bf2f(r0.x), bf2f(r0.y), bf2f(r0.z), bf2f(r0.w)};
  float i1[4] = {bf2f(r1.x), bf2f(r1.y), bf2f(r1.z), bf2f(r1.w)};
  float i2[4] = {bf2f(r2.x), bf2f(r2.y), bf2f(r2.z), bf2f(r2.w)};
  float i3[4] = {bf2f(r3.x), bf2f(r3.y), bf2f(r3.z), bf2f(r3.w)};
  ushort4 o;
  unsigned short* op = (unsigned short*)&o;
#pragma unroll
  for (int ch = 0; ch < 4; ++ch) {
    int c = c4 + ch;
    float4 w = *(const float4*)&cw[c * 4];
    float v = cb[c];
    v = fmaf(i0[ch], w.x, v);
    v = fmaf(i1[ch], w.y, v);
    v = fmaf(i2[ch], w.z, v);
    v = fmaf(i3[ch], w.w, v);
    v = v / (1.f + expf(-v));
    op[ch] = f2bf(v);
  }
  if (c4 < Ii) *(ushort4*)&Xr[(size_t)row * Ii + c4] = o;
  else if (c4 < Ii + GNn) *(ushort4*)&Bb[(size_t)row * GNn + (c4 - Ii)] = o;
  else *(ushort4*)&Cb[(size_t)row * GNn + (c4 - Ii - GNn)] = o;
}

// ---------------- softplus(dt)+bias, A*dt chunk cumsum ----------------
__global__ __launch_bounds__(256) void dt_cumsum(const float* __restrict__ dtraw,
                                                 const float* __restrict__ dt_bias,
                                                 const float* __restrict__ A_log,
                                                 float* __restrict__ dtbuf,
                                                 float* __restrict__ Acum) {
  int bc = blockIdx.x;   // b*8+c
  int h = blockIdx.y;
  int l = threadIdx.x;
  int row = bc * CHc + l;
  float xv = dtraw[(size_t)row * Hh + h] + dt_bias[h];
  float dt = (xv > 20.f) ? xv : log1pf(expf(xv));
  dtbuf[(size_t)row * Hh + h] = dt;
  float a = -expf(A_log[h]) * dt;
  __shared__ float buf[CHc];
  buf[l] = a;
  __syncthreads();
  for (int off = 1; off < CHc; off <<= 1) {
    float v = (l >= off) ? buf[l - off] : 0.f;
    __syncthreads();
    buf[l] += v;
    __syncthreads();
  }
  Acum[((size_t)bc * Hh + h) * CHc + l] = buf[l];
}

// ---------------- per-chunk states via MFMA ----------------
// Computes S_T[p][n] = sum_l (w[l]*X[l,p]) * B[l,n]  ([p][n] layout)
__global__ __launch_bounds__(256, 2) void states_kernel(const unsigned short* __restrict__ Xraw,
                                                        const unsigned short* __restrict__ Bbuf,
                                                        const float* __restrict__ dtbuf,
                                                        const float* __restrict__ Acum,
                                                        unsigned short* __restrict__ states) {
  int bch = blockIdx.x;            // (b*8+c)*32 + h
  int h = bch & 31, bc = bch >> 5;
  int g = h & 7;
  int rowbase = bc * CHc;
  const float* Ac = Acum + (size_t)bch * CHc;
  __shared__ unsigned short XTt[128 * 136];  // [p][l] weighted (A-op)
  __shared__ unsigned short BTt[128 * 136];  // [n][l] (B-op)
  __shared__ float wl[128];
  int t = threadIdx.x;
  int wid = t >> 6, lane = t & 63, q = lane >> 4, l16 = lane & 15;
  float Alast = Ac[CHc - 1];
  floatx4 acc[8][2] = {};
  for (int lt = 0; lt < 2; ++lt) {
    int l0 = lt * 128;
    if (t < 128)
      wl[t] = dtbuf[(size_t)(rowbase + l0 + t) * Hh + h] * __expf(Alast - Ac[l0 + t]);
    __syncthreads();
    for (int i = t; i < 2048; i += 256) {
      int r = i >> 4, c8 = (i & 15) * 8;
      int row = rowbase + l0 + r;
      const unsigned short* xp = &Xraw[(size_t)row * Ii + h * Pp + c8];
      const unsigned short* bp = &Bbuf[(size_t)row * GNn + g * Nn + c8];
      ushort4 xa = *(const ushort4*)xp;
      ushort4 xb = *(const ushort4*)(xp + 4);
      ushort4 ba = *(const ushort4*)bp;
      ushort4 bb = *(const ushort4*)(bp + 4);
      float w = wl[r];
      XTt[(c8 + 0) * 136 + r] = f2bf(bf2f(xa.x) * w);
      XTt[(c8 + 1) * 136 + r] = f2bf(bf2f(xa.y) * w);
      XTt[(c8 + 2) * 136 + r] = f2bf(bf2f(xa.z) * w);
      XTt[(c8 + 3) * 136 + r] = f2bf(bf2f(xa.w) * w);
      XTt[(c8 + 4) * 136 + r] = f2bf(bf2f(xb.x) * w);
      XTt[(c8 + 5) * 136 + r] = f2bf(bf2f(xb.y) * w);
      XTt[(c8 + 6) * 136 + r] = f2bf(bf2f(xb.z) * w);
      XTt[(c8 + 7) * 136 + r] = f2bf(bf2f(xb.w) * w);
      BTt[(c8 + 0) * 136 + r] = ba.x;
      BTt[(c8 + 1) * 136 + r] = ba.y;
      BTt[(c8 + 2) * 136 + r] = ba.z;
      BTt[(c8 + 3) * 136 + r] = ba.w;
      BTt[(c8 + 4) * 136 + r] = bb.x;
      BTt[(c8 + 5) * 136 + r] = bb.y;
      BTt[(c8 + 6) * 136 + r] = bb.z;
      BTt[(c8 + 7) * 136 + r] = bb.w;
    }
    __syncthreads();
#pragma unroll
    for (int kk = 0; kk < 128; kk += 32) {
      int ko = kk + q * 8;
      short8 af[8];
#pragma unroll
      for (int mt = 0; mt < 8; ++mt)
        af[mt] = *(const short8*)&XTt[(mt * 16 + l16) * 136 + ko];
      short8 b0 = *(const short8*)&BTt[(wid * 32 + l16) * 136 + ko];
      short8 b1 = *(const short8*)&BTt[(wid * 32 + 16 + l16) * 136 + ko];
#pragma unroll
      for (int mt = 0; mt < 8; ++mt) {
        acc[mt][0] = __builtin_amdgcn_mfma_f32_16x16x32_bf16(af[mt], b0, acc[mt][0], 0, 0, 0);
        acc[mt][1] = __builtin_amdgcn_mfma_f32_16x16x32_bf16(af[mt], b1, acc[mt][1], 0, 0, 0);
      }
    }
  }
  unsigned short* so = states + (size_t)bch * (Nn * Pp);
#pragma unroll
  for (int mt = 0; mt < 8; ++mt)
#pragma unroll
    for (int nt = 0; nt < 2; ++nt)
#pragma unroll
      for (int r = 0; r < 4; ++r)
        so[(size_t)(mt * 16 + q * 4 + r) * Nn + wid * 32 + nt * 16 + l16] =
            f2bf(acc[mt][nt][r]);
}

// ---------------- sequential chunk recurrence -> states_prev ([p][n] layout) ----------------
__global__ __launch_bounds__(256) void chunk_scan(const unsigned short* __restrict__ states,
                                                  const float* __restrict__ Acum,
                                                  unsigned short* __restrict__ sprev) {
  int bh = blockIdx.x;  // b*32+h
  int b = bh >> 5, h = bh & 31;
  float dec[NCn];
#pragma unroll
  for (int c = 0; c < NCn; ++c)
    dec[c] = expf(Acum[((size_t)((b * NCn + c) * Hh + h)) * CHc + (CHc - 1)]);
  int e0 = blockIdx.y * 2048 + threadIdx.x;
  for (int e = e0; e < (int)(blockIdx.y + 1) * 2048; e += 256) {
    float S = 0.f;
#pragma unroll
    for (int c = 0; c < NCn; ++c) {
      size_t off = ((size_t)((b * NCn + c) * Hh + h)) * (Nn * Pp) + e;
      sprev[off] = f2bf(S);
      S = fmaf(dec[c], S, bf2f(states[off]));
    }
  }
}

// ---------------- Y = Y_diag + Y_off via MFMA, per (b,c,h,ltile128) ----------------
// 512 threads (8 waves, 16 p-cols each); Gs aliases Bt; 100 KB LDS.
__global__ __launch_bounds__(512, 1) void y_kernel(const unsigned short* __restrict__ Xraw,
                                                   const unsigned short* __restrict__ Bbuf,
                                                   const unsigned short* __restrict__ Cbuf,
                                                   const float* __restrict__ dtbuf,
                                                   const float* __restrict__ Acum,
                                                   const unsigned short* __restrict__ sprev,
                                                   unsigned short* __restrict__ ybuf) {
  int bid = blockIdx.x;
  int lt = bid & 1;
  int bch = bid >> 1;
  int h = bch & 31, bc = bch >> 5;
  int g = h & 7;
  int rowbase = bc * CHc;
  int l0 = lt * 128;
  const float* Ac = Acum + (size_t)bch * CHc;

  __shared__ unsigned short Ct[128 * 128];   // [l][n]
  __shared__ unsigned short Bt[128 * 128];   // [s][n] during GEMM1; Gs [l][s]; sprev [p][n]
  __shared__ unsigned short Xt[128 * 136];   // [p][s]
  __shared__ float Acl[128], Aex[128], Ast[128], dts[128];
  unsigned short* Gs = Bt;

  int t = threadIdx.x;
  int wid = t >> 6, lane = t & 63, q = lane >> 4, l16 = lane & 15;

  for (int i = t; i < 2048; i += 512) {
    int r = i >> 4, c8 = (i & 15) * 8;
    *(uint4*)&Ct[r * 128 + c8] =
        *(const uint4*)&Cbuf[(size_t)(rowbase + l0 + r) * GNn + g * Nn + c8];
  }
  if (t < 128) {
    float a = Ac[l0 + t];
    Acl[t] = a;
    Aex[t] = __expf(a);
  }

  floatx4 acc[8] = {};

  for (int st = 0; st <= lt; ++st) {
    int s0 = st * 128;
    __syncthreads();   // prior GEMM2 (reads Gs=Bt) and staging consumers done
    for (int i = t; i < 2048; i += 512) {
      int r = i >> 4, c8 = (i & 15) * 8;
      int row = rowbase + s0 + r;
      *(uint4*)&Bt[r * 128 + c8] =
          *(const uint4*)&Bbuf[(size_t)row * GNn + g * Nn + c8];
      const unsigned short* xp = &Xraw[(size_t)row * Ii + h * Pp + c8];
      ushort4 xa = *(const ushort4*)xp;
      ushort4 xb = *(const ushort4*)(xp + 4);
      Xt[(c8 + 0) * 136 + r] = xa.x;
      Xt[(c8 + 1) * 136 + r] = xa.y;
      Xt[(c8 + 2) * 136 + r] = xa.z;
      Xt[(c8 + 3) * 136 + r] = xa.w;
      Xt[(c8 + 4) * 136 + r] = xb.x;
      Xt[(c8 + 5) * 136 + r] = xb.y;
      Xt[(c8 + 6) * 136 + r] = xb.z;
      Xt[(c8 + 7) * 136 + r] = xb.w;
    }
    if (t < 128) {
      Ast[t] = Ac[s0 + t];
      dts[t] = dtbuf[(size_t)(rowbase + s0 + t) * Hh + h];
    }
    __syncthreads();
    // GEMM1: G = C · B^T   (this wave's s-cols: wid*16..wid*16+15)
    floatx4 gacc[8] = {};
#pragma unroll
    for (int kk = 0; kk < 128; kk += 32) {
      int ko = kk + q * 8;
      short8 af[8];
#pragma unroll
      for (int mt = 0; mt < 8; ++mt)
        af[mt] = *(const short8*)&Ct[(mt * 16 + l16) * 128 + ko];
      short8 b0 = *(const short8*)&Bt[(wid * 16 + l16) * 128 + ko];
#pragma unroll
      for (int mt = 0; mt < 8; ++mt)
        gacc[mt] = __builtin_amdgcn_mfma_f32_16x16x32_bf16(af[mt], b0, gacc[mt], 0, 0, 0);
    }
    __syncthreads();   // all waves done reading Bt before Gs overwrite
    bool diag = (st == lt);
#pragma unroll
    for (int mt = 0; mt < 8; ++mt)
#pragma unroll
      for (int r = 0; r < 4; ++r) {
        int l_loc = mt * 16 + q * 4 + r;
        int s_loc = wid * 16 + l16;
        float v = gacc[mt][r] * dts[s_loc] * __expf(Acl[l_loc] - Ast[s_loc]);
        Gs[l_loc * 128 + s_loc] = (!diag || s_loc <= l_loc) ? f2bf(v) : (unsigned short)0;
      }
    __syncthreads();
    // GEMM2: Y += G · X   (A = Gs [l][s], B-op = Xt [p][s])
#pragma unroll
    for (int kk = 0; kk < 128; kk += 32) {
      int ko = kk + q * 8;
      short8 af[8];
#pragma unroll
      for (int mt = 0; mt < 8; ++mt)
        af[mt] = *(const short8*)&Gs[(mt * 16 + l16) * 128 + ko];
      short8 b0 = *(const short8*)&Xt[(wid * 16 + l16) * 136 + ko];
#pragma unroll
      for (int mt = 0; mt < 8; ++mt)
        acc[mt] = __builtin_amdgcn_mfma_f32_16x16x32_bf16(af[mt], b0, acc[mt], 0, 0, 0);
    }
  }
  __syncthreads();   // last GEMM2 done before overwriting Bt(=Gs) with sprev
  // scale Ct rows by exp(Acum[l]); stage sprev [p][n] into Bt
  for (int i = t; i < 2048; i += 512) {
    int r = i >> 4;
    uint4 cv = *(uint4*)&Ct[i * 8];
    unsigned short* cp = (unsigned short*)&cv;
    float e = Aex[r];
#pragma unroll
    for (int j = 0; j < 8; ++j) cp[j] = f2bf(bf2f(cp[j]) * e);
    *(uint4*)&Ct[i * 8] = cv;
    *(uint4*)&Bt[i * 8] = *(const uint4*)&sprev[(size_t)bch * (Nn * Pp) + (size_t)i * 8];
  }
  __syncthreads();
  // Y_off: Y += C~ · Sprev   (A = scaled Ct [l][n], B-op = Bt [p][n])
#pragma unroll
  for (int kk = 0; kk < 128; kk += 32) {
    int ko = kk + q * 8;
    short8 af[8];
#pragma unroll
    for (int mt = 0; mt < 8; ++mt)
      af[mt] = *(const short8*)&Ct[(mt * 16 + l16) * 128 + ko];
    short8 b0 = *(const short8*)&Bt[(wid * 16 + l16) * 128 + ko];
#pragma unroll
    for (int mt = 0; mt < 8; ++mt)
      acc[mt] = __builtin_amdgcn_mfma_f32_16x16x32_bf16(af[mt], b0, acc[mt], 0, 0, 0);
  }
  // epilogue: Y_diag + Y_off (D*X added in norm_kernel)
#pragma unroll
  for (int mt = 0; mt < 8; ++mt)
#pragma unroll
    for (int r = 0; r < 4; ++r) {
      int row = rowbase + l0 + mt * 16 + q * 4 + r;
      int col = h * Pp + wid * 16 + l16;
      ybuf[(size_t)row * Ii + col] = f2bf(acc[mt][r]);
    }
}

// ---------------- gated group RMSNorm (adds D*X) -> bf16 ----------------
// NOTE: xraw and normed alias — each element read-before-write by its own thread.
__global__ __launch_bounds__(256) void norm_kernel(const unsigned short* ybuf,
                                                   const unsigned short* gate_bf,
                                                   const unsigned short* xraw,
                                                   const float* Dvec,
                                                   const float* norm_w,
                                                   unsigned short* normed) {
  int blk = blockIdx.x;  // row*8 + grp
  int row = blk >> 3, grp = blk & 7;
  size_t base = (size_t)row * Ii + grp * 512;
  int t = threadIdx.x;
  int col0 = grp * 512 + t, col1 = col0 + 256;
  float D0 = Dvec[col0 >> 7], D1 = Dvec[col1 >> 7];
  float y0 = bf2f(ybuf[base + t]) + D0 * bf2f(xraw[base + t]);
  float y1 = bf2f(ybuf[base + t + 256]) + D1 * bf2f(xraw[base + t + 256]);
  float g0 = bf2f(gate_bf[base + t]), g1 = bf2f(gate_bf[base + t + 256]);
  float h0 = y0 * (g0 / (1.f + expf(-g0)));
  float h1 = y1 * (g1 / (1.f + expf(-g1)));
  __shared__ float red[256];
  red[t] = h0 * h0 + h1 * h1;
  __syncthreads();
  for (int off = 128; off > 0; off >>= 1) {
    if (t < off) red[t] += red[t + off];
    __syncthreads();
  }
  float scale = rsqrtf(red[0] / 512.f + 1e-6f);
  normed[base + t] = f2bf(h0 * scale * norm_w[grp * 512 + t]);
  normed[base + t + 256] = f2bf(h1 * scale * norm_w[grp * 512 + t + 256]);
}

extern "C" void kernel_launch(void* const* d_in, const int* in_sizes, int n_in,
                              void* d_out, int out_size, void* d_ws, size_t ws_size,
                              hipStream_t stream) {
  const float* x    = (const float*)d_in[0];
  const float* W1   = (const float*)d_in[1];
  const float* cw   = (const float*)d_in[2];
  const float* cb   = (const float*)d_in[3];
  const float* dtb  = (const float*)d_in[4];
  const float* Alog = (const float*)d_in[5];
  const float* Dv   = (const float*)d_in[6];
  const float* nw   = (const float*)d_in[7];
  const float* W2   = (const float*)d_in[8];
  float* out = (float*)d_out;
  char* ws = (char*)d_ws;

  // ws layout (bytes), total ~185.5 MiB (known-good).
  const size_t o_xbf   = 0;                        // 16,777,216
  const size_t o_w1    = 16777216ull;              // 41,943,040
  const size_t o_gate  = o_w1 + 41943040ull;       // 33,554,432
  const size_t o_hbc   = o_gate + 33554432ull;     // 50,331,648
  const size_t o_xraw  = o_hbc + 50331648ull;      // 33,554,432
  const size_t o_b     = o_xraw + 33554432ull;     // 8,388,608
  const size_t o_c     = o_b + 8388608ull;         // 8,388,608
  const size_t o_dtraw = o_c + 8388608ull;         // 524,288
  const size_t o_dt    = o_dtraw + 524288ull;      // 524,288
  const size_t o_acum  = o_dt + 524288ull;         // 524,288
  const size_t total   = o_acum + 524288ull;       // 194,510,848
  if (ws_size < total) {
    ws_probe<<<1, 1, 0, stream>>>(out, (float)(ws_size >> 20));
    return;
  }

  unsigned short* xbf    = (unsigned short*)(ws + o_xbf);
  unsigned short* w1bf   = (unsigned short*)(ws + o_w1);
  unsigned short* states = (unsigned short*)(ws + o_w1);               // alias
  unsigned short* sprev  = (unsigned short*)(ws + o_w1 + 16777216ull); // alias
  unsigned short* w2bf   = (unsigned short*)(ws + o_w1);               // alias (late)
  unsigned short* gatebf = (unsigned short*)(ws + o_gate);
  unsigned short* hbc    = (unsigned short*)(ws + o_hbc);
  unsigned short* ybuf   = (unsigned short*)(ws + o_hbc);              // alias
  unsigned short* xraw   = (unsigned short*)(ws + o_xraw);
  unsigned short* normed = (unsigned short*)(ws + o_xraw);             // alias (late)
  unsigned short* bbuf   = (unsigned short*)(ws + o_b);
  unsigned short* cbuf   = (unsigned short*)(ws + o_c);
  float* dtraw  = (float*)(ws + o_dtraw);
  float* dtbuf  = (float*)(ws + o_dt);
  float* acum   = (float*)(ws + o_acum);

  // 1. W1 convert (x convert fused into dt_gemv)
  cvt_bf16<<<dim3(20480), dim3(256), 0, stream>>>(W1, w1bf, (size_t)5242880);
  // 2. exact dt columns (fp32) + x->bf16
  dt_gemv<<<dim3(Mm), dim3(256), 0, stream>>>(x, W1, dtraw, xbf);
  // 3. GEMM1 -> gate(bf16) + hbc(bf16)   [supergroup-swizzled 1-D grid]
  gemm_bt<<<dim3((Mm / BM) * (NG1 / BN)), dim3(256), 0, stream>>>(
      xbf, w1bf, Ee, NG1 / BN, 1, nullptr, gatebf, hbc, 0);
  // 4. conv + silu -> X, B, C (bf16)
  conv_silu<<<dim3((Mm * CDd / 4) / 256), dim3(256), 0, stream>>>(hbc, cw, cb, xraw, bbuf, cbuf);
  // 5. dt softplus + A*dt cumsum
  dt_cumsum<<<dim3(16, Hh), dim3(CHc), 0, stream>>>(dtraw, dtb, Alog, dtbuf, acum);
  // 6. per-chunk states (MFMA, [p][n]; overwrites w1bf — GEMM1 done)
  states_kernel<<<dim3(512), dim3(256), 0, stream>>>(xraw, bbuf, dtbuf, acum, states);
  // 7. chunk recurrence
  chunk_scan<<<dim3(64, 8), dim3(256), 0, stream>>>(states, acum, sprev);
  // 8. convert W2 into states' slot (states dead; sprev untouched)
  cvt_bf16<<<dim3(8192), dim3(256), 0, stream>>>(W2, w2bf, (size_t)2097152);
  // 9. Y (MFMA, 512 threads)
  y_kernel<<<dim3(1024), dim3(512), 0, stream>>>(xraw, bbuf, cbuf, dtbuf, acum, sprev, ybuf);
  // 10. gated RMSNorm (+ D*X) -> bf16 (normed overwrites xraw after read)
  norm_kernel<<<dim3(Mm * 8), dim3(256), 0, stream>>>(ybuf, gatebf, xraw, Dv, nw, normed);
  // 11. GEMM2 -> out (fp32)
  gemm_bt<<<dim3((Mm / BM) * (Ee / BN)), dim3(256), 0, stream>>>(
      normed, w2bf, Ii, Ee / BN, 0, out, nullptr, nullptr, Ee);
}

// Round 5
// 799.326 us; speedup vs baseline: 1.1721x; 1.1721x over previous
//
#include <hip/hip_runtime.h>
#include <stdint.h>

// Problem constants
#define Hh 32
#define Pp 128
#define Nn 128
#define Gg 8
#define Kk 4
#define CHc 256
#define Ee 2048
#define Ii 4096
#define CDd 6144
#define Mm 4096        // b*s = 2*2048
#define NCn 8
#define GNn 1024
#define NG1 10240      // gate+hbc columns (dt columns done in fp32 gemv)

using short8  = __attribute__((ext_vector_type(8))) short;
using floatx4 = __attribute__((ext_vector_type(4))) float;

__device__ __forceinline__ unsigned short f2bf(float f) {
  unsigned u = __float_as_uint(f);
  u += 0x7FFF + ((u >> 16) & 1);           // round-to-nearest-even
  return (unsigned short)(u >> 16);
}
__device__ __forceinline__ float bf2f(unsigned short s) {
  return __uint_as_float(((unsigned)s) << 16);
}
__device__ __forceinline__ void gld_lds16(void* lds, const void* g) {
  __builtin_amdgcn_global_load_lds(
      (const __attribute__((address_space(1))) void*)g,
      (__attribute__((address_space(3))) void*)lds, 16, 0, 0);
}

// ws probe: if workspace too small, expose its MB count as d_out[0]
__global__ void ws_probe(float* out, float mb) { out[0] = mb; }

// ---------------- convert fp32 -> bf16 (vectorized) ----------------
__global__ __launch_bounds__(256) void cvt_bf16(const float* __restrict__ src,
                                                unsigned short* __restrict__ dst,
                                                size_t n4) {
  size_t i = (size_t)blockIdx.x * 256 + threadIdx.x;
  if (i < n4) {
    float4 v = ((const float4*)src)[i];
    ushort4 o;
    o.x = f2bf(v.x); o.y = f2bf(v.y); o.z = f2bf(v.z); o.w = f2bf(v.w);
    ((ushort4*)dst)[i] = o;
  }
}

// ---------------- exact fp32 GEMV for dt columns + fused x->bf16 ----------------
__global__ __launch_bounds__(256) void dt_gemv(const float* __restrict__ x,
                                               const float* __restrict__ W1,
                                               float* __restrict__ dtraw,
                                               unsigned short* __restrict__ xbf) {
  int row = blockIdx.x;
  __shared__ float xs[Ee];
  for (int i = threadIdx.x; i < Ee / 4; i += 256) {
    float4 v = ((const float4*)(x + (size_t)row * Ee))[i];
    ((float4*)xs)[i] = v;
    ushort4 o;
    o.x = f2bf(v.x); o.y = f2bf(v.y); o.z = f2bf(v.z); o.w = f2bf(v.w);
    ((ushort4*)(xbf + (size_t)row * Ee))[i] = o;
  }
  __syncthreads();
  int h = threadIdx.x >> 3, seg = threadIdx.x & 7;
  const float* wr = W1 + (size_t)(NG1 + h) * Ee;
  float s = 0.f;
  for (int k = seg; k < Ee; k += 8) s = fmaf(xs[k], wr[k], s);
  s += __shfl_xor(s, 1);
  s += __shfl_xor(s, 2);
  s += __shfl_xor(s, 4);
  if (seg == 0) dtraw[(size_t)row * Hh + h] = s;
}

// ---------------- bf16 MFMA GEMM, B given as N x K (B^T pattern) ----------------
// XOR-swizzled LDS: chunk c holds k-octet ((c&7)^((c>>3)&7)) of row c>>3.
// Reads add xo = ((k8 ^ (l16&7))<<3) — spreads 16 fragment lanes over all 8
// bank quads (2-way, free) instead of 16-way conflicts at stride 128B.
// mode 0: plain fp32 out (pitch Nout).  mode 1: split epilogue gate/hbc (bf16).
#define BM 128
#define BN 128
#define BK 64
__global__ __launch_bounds__(256) void gemm_bt(const unsigned short* __restrict__ A,
                                               const unsigned short* __restrict__ B,
                                               int K, int mode,
                                               float* __restrict__ out_f,
                                               unsigned short* __restrict__ out_gate,
                                               unsigned short* __restrict__ out_hbc,
                                               int Nout) {
  __shared__ unsigned short As[BM * BK];
  __shared__ unsigned short Bs[BN * BK];
  const int tid = threadIdx.x;
  const int wid = tid >> 6, lane = tid & 63;
  const int q = lane >> 4, l16 = lane & 15;
  const int m0 = blockIdx.y * BM;
  const int n0 = blockIdx.x * BN;
  floatx4 acc[8][2] = {};

  const int cb = tid & 192;  // wave-uniform chunk base bits (= wid*64)
  // per-lane swizzled k-octet for staging: lane's chunk = chunkbase + lane
  for (int k0 = 0; k0 < K; k0 += BK) {
    __syncthreads();
#pragma unroll
    for (int it = 0; it < 4; ++it) {
      int chunkbase = it * 256 + cb;
      int chunk = chunkbase + lane;
      int m = chunk >> 3;
      int k8d = (chunk & 7) ^ (m & 7);       // swizzled data octet
      gld_lds16(&As[chunkbase * 8], &A[(size_t)(m0 + m) * K + k0 + (k8d << 3)]);
      gld_lds16(&Bs[chunkbase * 8], &B[(size_t)(n0 + m) * K + k0 + (k8d << 3)]);
    }
    __syncthreads();
#pragma unroll
    for (int kk = 0; kk < BK; kk += 32) {
      const int k8 = (kk >> 3) + q;
      const int xo = ((k8 ^ (l16 & 7)) << 3);   // swizzled in-row offset (shorts)
      short8 af[8];
#pragma unroll
      for (int mt = 0; mt < 8; ++mt)
        af[mt] = *(const short8*)&As[(mt * 16 + l16) * BK + xo];
      short8 bf0 = *(const short8*)&Bs[(wid * 32 + l16) * BK + xo];
      short8 bf1 = *(const short8*)&Bs[(wid * 32 + 16 + l16) * BK + xo];
#pragma unroll
      for (int mt = 0; mt < 8; ++mt) {
        acc[mt][0] = __builtin_amdgcn_mfma_f32_16x16x32_bf16(af[mt], bf0, acc[mt][0], 0, 0, 0);
        acc[mt][1] = __builtin_amdgcn_mfma_f32_16x16x32_bf16(af[mt], bf1, acc[mt][1], 0, 0, 0);
      }
    }
  }
#pragma unroll
  for (int mt = 0; mt < 8; ++mt)
#pragma unroll
    for (int nt = 0; nt < 2; ++nt)
#pragma unroll
      for (int r = 0; r < 4; ++r) {
        int row = m0 + mt * 16 + q * 4 + r;
        int col = n0 + wid * 32 + nt * 16 + l16;
        float v = acc[mt][nt][r];
        if (mode == 0) {
          out_f[(size_t)row * Nout + col] = v;
        } else {
          if (col < Ii) out_gate[(size_t)row * Ii + col] = f2bf(v);
          else out_hbc[(size_t)row * CDd + (col - Ii)] = f2bf(v);
        }
      }
}

// ---------------- depthwise causal conv K=4 + bias + silu, split bf16 outputs ----------------
__global__ __launch_bounds__(256) void conv_silu(const unsigned short* __restrict__ hbc,
                                                 const float* __restrict__ cw,
                                                 const float* __restrict__ cb,
                                                 unsigned short* __restrict__ Xr,
                                                 unsigned short* __restrict__ Bb,
                                                 unsigned short* __restrict__ Cb) {
  int idx = blockIdx.x * 256 + threadIdx.x;   // over Mm*CDd/4
  int c4 = (idx % (CDd / 4)) * 4;
  int row = idx / (CDd / 4);
  int s = row & 2047;
  const unsigned short* base = hbc + (size_t)row * CDd + c4;
  ushort4 zero = {0, 0, 0, 0};
  ushort4 r0 = (s >= 3) ? *(const ushort4*)(base - (size_t)3 * CDd) : zero;
  ushort4 r1 = (s >= 2) ? *(const ushort4*)(base - (size_t)2 * CDd) : zero;
  ushort4 r2 = (s >= 1) ? *(const ushort4*)(base - (size_t)1 * CDd) : zero;
  ushort4 r3 = *(const ushort4*)base;
  float i0[4] = {bf2f(r0.x), bf2f(r0.y), bf2f(r0.z), bf2f(r0.w)};
  float i1[4] = {bf2f(r1.x), bf2f(r1.y), bf2f(r1.z), bf2f(r1.w)};
  float i2[4] = {bf2f(r2.x), bf2f(r2.y), bf2f(r2.z), bf2f(r2.w)};
  float i3[4] = {bf2f(r3.x), bf2f(r3.y), bf2f(r3.z), bf2f(r3.w)};
  ushort4 o;
  unsigned short* op = (unsigned short*)&o;
#pragma unroll
  for (int ch = 0; ch < 4; ++ch) {
    int c = c4 + ch;
    float4 w = *(const float4*)&cw[c * 4];
    float v = cb[c];
    v = fmaf(i0[ch], w.x, v);
    v = fmaf(i1[ch], w.y, v);
    v = fmaf(i2[ch], w.z, v);
    v = fmaf(i3[ch], w.w, v);
    v = v / (1.f + expf(-v));
    op[ch] = f2bf(v);
  }
  if (c4 < Ii) *(ushort4*)&Xr[(size_t)row * Ii + c4] = o;
  else if (c4 < Ii + GNn) *(ushort4*)&Bb[(size_t)row * GNn + (c4 - Ii)] = o;
  else *(ushort4*)&Cb[(size_t)row * GNn + (c4 - Ii - GNn)] = o;
}

// ---------------- softplus(dt)+bias, A*dt chunk cumsum ----------------
__global__ __launch_bounds__(256) void dt_cumsum(const float* __restrict__ dtraw,
                                                 const float* __restrict__ dt_bias,
                                                 const float* __restrict__ A_log,
                                                 float* __restrict__ dtbuf,
                                                 float* __restrict__ Acum) {
  int bc = blockIdx.x;   // b*8+c
  int h = blockIdx.y;
  int l = threadIdx.x;
  int row = bc * CHc + l;
  float xv = dtraw[(size_t)row * Hh + h] + dt_bias[h];
  float dt = (xv > 20.f) ? xv : log1pf(expf(xv));
  dtbuf[(size_t)row * Hh + h] = dt;
  float a = -expf(A_log[h]) * dt;
  __shared__ float buf[CHc];
  buf[l] = a;
  __syncthreads();
  for (int off = 1; off < CHc; off <<= 1) {
    float v = (l >= off) ? buf[l - off] : 0.f;
    __syncthreads();
    buf[l] += v;
    __syncthreads();
  }
  Acum[((size_t)bc * Hh + h) * CHc + l] = buf[l];
}

// ---------------- per-chunk states via MFMA ----------------
// S_T[p][n] = sum_l (w[l]*X[l,p]) * B[l,n]  ([p][n] layout)
__global__ __launch_bounds__(256, 2) void states_kernel(const unsigned short* __restrict__ Xraw,
                                                        const unsigned short* __restrict__ Bbuf,
                                                        const float* __restrict__ dtbuf,
                                                        const float* __restrict__ Acum,
                                                        unsigned short* __restrict__ states) {
  int bch = blockIdx.x;            // (b*8+c)*32 + h
  int h = bch & 31, bc = bch >> 5;
  int g = h & 7;
  int rowbase = bc * CHc;
  const float* Ac = Acum + (size_t)bch * CHc;
  __shared__ unsigned short XTt[128 * 136];  // [p][l] weighted (A-op)
  __shared__ unsigned short BTt[128 * 136];  // [n][l] (B-op)
  __shared__ float wl[128];
  int t = threadIdx.x;
  int wid = t >> 6, lane = t & 63, q = lane >> 4, l16 = lane & 15;
  float Alast = Ac[CHc - 1];
  floatx4 acc[8][2] = {};
  for (int lt = 0; lt < 2; ++lt) {
    int l0 = lt * 128;
    if (t < 128)
      wl[t] = dtbuf[(size_t)(rowbase + l0 + t) * Hh + h] * __expf(Alast - Ac[l0 + t]);
    __syncthreads();
    for (int i = t; i < 2048; i += 256) {
      int r = i >> 4, c8 = (i & 15) * 8;
      int row = rowbase + l0 + r;
      const unsigned short* xp = &Xraw[(size_t)row * Ii + h * Pp + c8];
      const unsigned short* bp = &Bbuf[(size_t)row * GNn + g * Nn + c8];
      ushort4 xa = *(const ushort4*)xp;
      ushort4 xb = *(const ushort4*)(xp + 4);
      ushort4 ba = *(const ushort4*)bp;
      ushort4 bb = *(const ushort4*)(bp + 4);
      float w = wl[r];
      XTt[(c8 + 0) * 136 + r] = f2bf(bf2f(xa.x) * w);
      XTt[(c8 + 1) * 136 + r] = f2bf(bf2f(xa.y) * w);
      XTt[(c8 + 2) * 136 + r] = f2bf(bf2f(xa.z) * w);
      XTt[(c8 + 3) * 136 + r] = f2bf(bf2f(xa.w) * w);
      XTt[(c8 + 4) * 136 + r] = f2bf(bf2f(xb.x) * w);
      XTt[(c8 + 5) * 136 + r] = f2bf(bf2f(xb.y) * w);
      XTt[(c8 + 6) * 136 + r] = f2bf(bf2f(xb.z) * w);
      XTt[(c8 + 7) * 136 + r] = f2bf(bf2f(xb.w) * w);
      BTt[(c8 + 0) * 136 + r] = ba.x;
      BTt[(c8 + 1) * 136 + r] = ba.y;
      BTt[(c8 + 2) * 136 + r] = ba.z;
      BTt[(c8 + 3) * 136 + r] = ba.w;
      BTt[(c8 + 4) * 136 + r] = bb.x;
      BTt[(c8 + 5) * 136 + r] = bb.y;
      BTt[(c8 + 6) * 136 + r] = bb.z;
      BTt[(c8 + 7) * 136 + r] = bb.w;
    }
    __syncthreads();
#pragma unroll
    for (int kk = 0; kk < 128; kk += 32) {
      int ko = kk + q * 8;
      short8 af[8];
#pragma unroll
      for (int mt = 0; mt < 8; ++mt)
        af[mt] = *(const short8*)&XTt[(mt * 16 + l16) * 136 + ko];
      short8 b0 = *(const short8*)&BTt[(wid * 32 + l16) * 136 + ko];
      short8 b1 = *(const short8*)&BTt[(wid * 32 + 16 + l16) * 136 + ko];
#pragma unroll
      for (int mt = 0; mt < 8; ++mt) {
        acc[mt][0] = __builtin_amdgcn_mfma_f32_16x16x32_bf16(af[mt], b0, acc[mt][0], 0, 0, 0);
        acc[mt][1] = __builtin_amdgcn_mfma_f32_16x16x32_bf16(af[mt], b1, acc[mt][1], 0, 0, 0);
      }
    }
  }
  unsigned short* so = states + (size_t)bch * (Nn * Pp);
#pragma unroll
  for (int mt = 0; mt < 8; ++mt)
#pragma unroll
    for (int nt = 0; nt < 2; ++nt)
#pragma unroll
      for (int r = 0; r < 4; ++r)
        so[(size_t)(mt * 16 + q * 4 + r) * Nn + wid * 32 + nt * 16 + l16] =
            f2bf(acc[mt][nt][r]);
}

// ---------------- sequential chunk recurrence -> states_prev ([p][n] layout) ----------------
__global__ __launch_bounds__(256) void chunk_scan(const unsigned short* __restrict__ states,
                                                  const float* __restrict__ Acum,
                                                  unsigned short* __restrict__ sprev) {
  int bh = blockIdx.x;  // b*32+h
  int b = bh >> 5, h = bh & 31;
  float dec[NCn];
#pragma unroll
  for (int c = 0; c < NCn; ++c)
    dec[c] = expf(Acum[((size_t)((b * NCn + c) * Hh + h)) * CHc + (CHc - 1)]);
  int e0 = blockIdx.y * 2048 + threadIdx.x;
  for (int e = e0; e < (int)(blockIdx.y + 1) * 2048; e += 256) {
    float S = 0.f;
#pragma unroll
    for (int c = 0; c < NCn; ++c) {
      size_t off = ((size_t)((b * NCn + c) * Hh + h)) * (Nn * Pp) + e;
      sprev[off] = f2bf(S);
      S = fmaf(dec[c], S, bf2f(states[off]));
    }
  }
}

// ---------------- Y = Y_diag + Y_off via MFMA, per (b,c,h,ltile128) ----------------
// 512 threads (8 waves, 16 p-cols each); Gs aliases Bt; stride 136 (bank-safe).
#define YS 136
__global__ __launch_bounds__(512, 1) void y_kernel(const unsigned short* __restrict__ Xraw,
                                                   const unsigned short* __restrict__ Bbuf,
                                                   const unsigned short* __restrict__ Cbuf,
                                                   const float* __restrict__ dtbuf,
                                                   const float* __restrict__ Acum,
                                                   const unsigned short* __restrict__ sprev,
                                                   unsigned short* __restrict__ ybuf) {
  int bid = blockIdx.x;
  int lt = bid & 1;
  int bch = bid >> 1;
  int h = bch & 31, bc = bch >> 5;
  int g = h & 7;
  int rowbase = bc * CHc;
  int l0 = lt * 128;
  const float* Ac = Acum + (size_t)bch * CHc;

  __shared__ unsigned short Ct[128 * YS];   // [l][n]
  __shared__ unsigned short Bt[128 * YS];   // [s][n] GEMM1; Gs [l][s]; sprev [p][n]
  __shared__ unsigned short Xt[128 * YS];   // [p][s]
  __shared__ float Acl[128], Aex[128], Ast[128], dts[128];
  unsigned short* Gs = Bt;

  int t = threadIdx.x;
  int wid = t >> 6, lane = t & 63, q = lane >> 4, l16 = lane & 15;

  for (int i = t; i < 2048; i += 512) {
    int r = i >> 4, c8 = (i & 15) * 8;
    *(uint4*)&Ct[r * YS + c8] =
        *(const uint4*)&Cbuf[(size_t)(rowbase + l0 + r) * GNn + g * Nn + c8];
  }
  if (t < 128) {
    float a = Ac[l0 + t];
    Acl[t] = a;
    Aex[t] = __expf(a);
  }

  floatx4 acc[8] = {};

  for (int st = 0; st <= lt; ++st) {
    int s0 = st * 128;
    __syncthreads();   // prior GEMM2 (reads Gs=Bt) done
    for (int i = t; i < 2048; i += 512) {
      int r = i >> 4, c8 = (i & 15) * 8;
      int row = rowbase + s0 + r;
      *(uint4*)&Bt[r * YS + c8] =
          *(const uint4*)&Bbuf[(size_t)row * GNn + g * Nn + c8];
      const unsigned short* xp = &Xraw[(size_t)row * Ii + h * Pp + c8];
      ushort4 xa = *(const ushort4*)xp;
      ushort4 xb = *(const ushort4*)(xp + 4);
      Xt[(c8 + 0) * YS + r] = xa.x;
      Xt[(c8 + 1) * YS + r] = xa.y;
      Xt[(c8 + 2) * YS + r] = xa.z;
      Xt[(c8 + 3) * YS + r] = xa.w;
      Xt[(c8 + 4) * YS + r] = xb.x;
      Xt[(c8 + 5) * YS + r] = xb.y;
      Xt[(c8 + 6) * YS + r] = xb.z;
      Xt[(c8 + 7) * YS + r] = xb.w;
    }
    if (t < 128) {
      Ast[t] = Ac[s0 + t];
      dts[t] = dtbuf[(size_t)(rowbase + s0 + t) * Hh + h];
    }
    __syncthreads();
    // GEMM1: G = C · B^T   (this wave's s-cols: wid*16..wid*16+15)
    floatx4 gacc[8] = {};
#pragma unroll
    for (int kk = 0; kk < 128; kk += 32) {
      int ko = kk + q * 8;
      short8 af[8];
#pragma unroll
      for (int mt = 0; mt < 8; ++mt)
        af[mt] = *(const short8*)&Ct[(mt * 16 + l16) * YS + ko];
      short8 b0 = *(const short8*)&Bt[(wid * 16 + l16) * YS + ko];
#pragma unroll
      for (int mt = 0; mt < 8; ++mt)
        gacc[mt] = __builtin_amdgcn_mfma_f32_16x16x32_bf16(af[mt], b0, gacc[mt], 0, 0, 0);
    }
    __syncthreads();   // all waves done reading Bt before Gs overwrite
    bool diag = (st == lt);
#pragma unroll
    for (int mt = 0; mt < 8; ++mt)
#pragma unroll
      for (int r = 0; r < 4; ++r) {
        int l_loc = mt * 16 + q * 4 + r;
        int s_loc = wid * 16 + l16;
        float v = gacc[mt][r] * dts[s_loc] * __expf(Acl[l_loc] - Ast[s_loc]);
        Gs[l_loc * YS + s_loc] = (!diag || s_loc <= l_loc) ? f2bf(v) : (unsigned short)0;
      }
    __syncthreads();
    // GEMM2: Y += G · X   (A = Gs [l][s], B-op = Xt [p][s])
#pragma unroll
    for (int kk = 0; kk < 128; kk += 32) {
      int ko = kk + q * 8;
      short8 af[8];
#pragma unroll
      for (int mt = 0; mt < 8; ++mt)
        af[mt] = *(const short8*)&Gs[(mt * 16 + l16) * YS + ko];
      short8 b0 = *(const short8*)&Xt[(wid * 16 + l16) * YS + ko];
#pragma unroll
      for (int mt = 0; mt < 8; ++mt)
        acc[mt] = __builtin_amdgcn_mfma_f32_16x16x32_bf16(af[mt], b0, acc[mt], 0, 0, 0);
    }
  }
  __syncthreads();   // last GEMM2 done before overwriting Bt(=Gs) with sprev
  // scale Ct rows by exp(Acum[l]); stage sprev [p][n] into Bt
  for (int i = t; i < 2048; i += 512) {
    int r = i >> 4, c8 = (i & 15) * 8;
    uint4 cv = *(uint4*)&Ct[r * YS + c8];
    unsigned short* cp = (unsigned short*)&cv;
    float e = Aex[r];
#pragma unroll
    for (int j = 0; j < 8; ++j) cp[j] = f2bf(bf2f(cp[j]) * e);
    *(uint4*)&Ct[r * YS + c8] = cv;
    *(uint4*)&Bt[r * YS + c8] =
        *(const uint4*)&sprev[(size_t)bch * (Nn * Pp) + (size_t)i * 8];
  }
  __syncthreads();
  // Y_off: Y += C~ · Sprev   (A = scaled Ct [l][n], B-op = Bt [p][n])
#pragma unroll
  for (int kk = 0; kk < 128; kk += 32) {
    int ko = kk + q * 8;
    short8 af[8];
#pragma unroll
    for (int mt = 0; mt < 8; ++mt)
      af[mt] = *(const short8*)&Ct[(mt * 16 + l16) * YS + ko];
    short8 b0 = *(const short8*)&Bt[(wid * 16 + l16) * YS + ko];
#pragma unroll
    for (int mt = 0; mt < 8; ++mt)
      acc[mt] = __builtin_amdgcn_mfma_f32_16x16x32_bf16(af[mt], b0, acc[mt], 0, 0, 0);
  }
  // epilogue: Y_diag + Y_off (D*X added in norm_kernel)
#pragma unroll
  for (int mt = 0; mt < 8; ++mt)
#pragma unroll
    for (int r = 0; r < 4; ++r) {
      int row = rowbase + l0 + mt * 16 + q * 4 + r;
      int col = h * Pp + wid * 16 + l16;
      ybuf[(size_t)row * Ii + col] = f2bf(acc[mt][r]);
    }
}

// ---------------- gated group RMSNorm (adds D*X) -> bf16 ----------------
// NOTE: xraw and normed alias — each element read-before-write by its own thread.
__global__ __launch_bounds__(256) void norm_kernel(const unsigned short* ybuf,
                                                   const unsigned short* gate_bf,
                                                   const unsigned short* xraw,
                                                   const float* Dvec,
                                                   const float* norm_w,
                                                   unsigned short* normed) {
  int blk = blockIdx.x;  // row*8 + grp
  int row = blk >> 3, grp = blk & 7;
  size_t base = (size_t)row * Ii + grp * 512;
  int t = threadIdx.x;
  int col0 = grp * 512 + t, col1 = col0 + 256;
  float D0 = Dvec[col0 >> 7], D1 = Dvec[col1 >> 7];
  float y0 = bf2f(ybuf[base + t]) + D0 * bf2f(xraw[base + t]);
  float y1 = bf2f(ybuf[base + t + 256]) + D1 * bf2f(xraw[base + t + 256]);
  float g0 = bf2f(gate_bf[base + t]), g1 = bf2f(gate_bf[base + t + 256]);
  float h0 = y0 * (g0 / (1.f + expf(-g0)));
  float h1 = y1 * (g1 / (1.f + expf(-g1)));
  __shared__ float red[256];
  red[t] = h0 * h0 + h1 * h1;
  __syncthreads();
  for (int off = 128; off > 0; off >>= 1) {
    if (t < off) red[t] += red[t + off];
    __syncthreads();
  }
  float scale = rsqrtf(red[0] / 512.f + 1e-6f);
  normed[base + t] = f2bf(h0 * scale * norm_w[grp * 512 + t]);
  normed[base + t + 256] = f2bf(h1 * scale * norm_w[grp * 512 + t + 256]);
}

extern "C" void kernel_launch(void* const* d_in, const int* in_sizes, int n_in,
                              void* d_out, int out_size, void* d_ws, size_t ws_size,
                              hipStream_t stream) {
  const float* x    = (const float*)d_in[0];
  const float* W1   = (const float*)d_in[1];
  const float* cw   = (const float*)d_in[2];
  const float* cb   = (const float*)d_in[3];
  const float* dtb  = (const float*)d_in[4];
  const float* Alog = (const float*)d_in[5];
  const float* Dv   = (const float*)d_in[6];
  const float* nw   = (const float*)d_in[7];
  const float* W2   = (const float*)d_in[8];
  float* out = (float*)d_out;
  char* ws = (char*)d_ws;

  // ws layout (bytes), total ~185.5 MiB (known-good).
  const size_t o_xbf   = 0;                        // 16,777,216
  const size_t o_w1    = 16777216ull;              // 41,943,040
  const size_t o_gate  = o_w1 + 41943040ull;       // 33,554,432
  const size_t o_hbc   = o_gate + 33554432ull;     // 50,331,648
  const size_t o_xraw  = o_hbc + 50331648ull;      // 33,554,432
  const size_t o_b     = o_xraw + 33554432ull;     // 8,388,608
  const size_t o_c     = o_b + 8388608ull;         // 8,388,608
  const size_t o_dtraw = o_c + 8388608ull;         // 524,288
  const size_t o_dt    = o_dtraw + 524288ull;      // 524,288
  const size_t o_acum  = o_dt + 524288ull;         // 524,288
  const size_t total   = o_acum + 524288ull;       // 194,510,848
  if (ws_size < total) {
    ws_probe<<<1, 1, 0, stream>>>(out, (float)(ws_size >> 20));
    return;
  }

  unsigned short* xbf    = (unsigned short*)(ws + o_xbf);
  unsigned short* w1bf   = (unsigned short*)(ws + o_w1);
  unsigned short* states = (unsigned short*)(ws + o_w1);               // alias
  unsigned short* sprev  = (unsigned short*)(ws + o_w1 + 16777216ull); // alias
  unsigned short* w2bf   = (unsigned short*)(ws + o_w1);               // alias (late)
  unsigned short* gatebf = (unsigned short*)(ws + o_gate);
  unsigned short* hbc    = (unsigned short*)(ws + o_hbc);
  unsigned short* ybuf   = (unsigned short*)(ws + o_hbc);              // alias
  unsigned short* xraw   = (unsigned short*)(ws + o_xraw);
  unsigned short* normed = (unsigned short*)(ws + o_xraw);             // alias (late)
  unsigned short* bbuf   = (unsigned short*)(ws + o_b);
  unsigned short* cbuf   = (unsigned short*)(ws + o_c);
  float* dtraw  = (float*)(ws + o_dtraw);
  float* dtbuf  = (float*)(ws + o_dt);
  float* acum   = (float*)(ws + o_acum);

  // 1. W1 convert (x convert fused into dt_gemv)
  cvt_bf16<<<dim3(20480), dim3(256), 0, stream>>>(W1, w1bf, (size_t)5242880);
  // 2. exact dt columns (fp32) + x->bf16
  dt_gemv<<<dim3(Mm), dim3(256), 0, stream>>>(x, W1, dtraw, xbf);
  // 3. GEMM1 -> gate(bf16) + hbc(bf16)   [2D grid, n-fastest — round-3 ordering]
  gemm_bt<<<dim3(NG1 / BN, Mm / BM), dim3(256), 0, stream>>>(
      xbf, w1bf, Ee, 1, nullptr, gatebf, hbc, 0);
  // 4. conv + silu -> X, B, C (bf16)
  conv_silu<<<dim3((Mm * CDd / 4) / 256), dim3(256), 0, stream>>>(hbc, cw, cb, xraw, bbuf, cbuf);
  // 5. dt softplus + A*dt cumsum
  dt_cumsum<<<dim3(16, Hh), dim3(CHc), 0, stream>>>(dtraw, dtb, Alog, dtbuf, acum);
  // 6. per-chunk states (MFMA, [p][n]; overwrites w1bf — GEMM1 done)
  states_kernel<<<dim3(512), dim3(256), 0, stream>>>(xraw, bbuf, dtbuf, acum, states);
  // 7. chunk recurrence
  chunk_scan<<<dim3(64, 8), dim3(256), 0, stream>>>(states, acum, sprev);
  // 8. convert W2 into states' slot (states dead; sprev untouched)
  cvt_bf16<<<dim3(8192), dim3(256), 0, stream>>>(W2, w2bf, (size_t)2097152);
  // 9. Y (MFMA, 512 threads)
  y_kernel<<<dim3(1024), dim3(512), 0, stream>>>(xraw, bbuf, cbuf, dtbuf, acum, sprev, ybuf);
  // 10. gated RMSNorm (+ D*X) -> bf16 (normed overwrites xraw after read)
  norm_kernel<<<dim3(Mm * 8), dim3(256), 0, stream>>>(ybuf, gatebf, xraw, Dv, nw, normed);
  // 11. GEMM2 -> out (fp32)
  gemm_bt<<<dim3(Ee / BN, Mm / BM), dim3(256), 0, stream>>>(
      normed, w2bf, Ii, 0, out, nullptr, nullptr, Ee);
}

// Round 6
// 777.447 us; speedup vs baseline: 1.2051x; 1.0281x over previous
//
#include <hip/hip_runtime.h>
#include <stdint.h>

// Problem constants
#define Hh 32
#define Pp 128
#define Nn 128
#define Gg 8
#define Kk 4
#define CHc 256
#define Ee 2048
#define Ii 4096
#define CDd 6144
#define Mm 4096        // b*s = 2*2048
#define NCn 8
#define GNn 1024
#define NG1 10240      // gate+hbc columns (dt columns done in fp32 gemv)

using short8  = __attribute__((ext_vector_type(8))) short;
using floatx4 = __attribute__((ext_vector_type(4))) float;

__device__ __forceinline__ unsigned short f2bf(float f) {
  unsigned u = __float_as_uint(f);
  u += 0x7FFF + ((u >> 16) & 1);           // round-to-nearest-even
  return (unsigned short)(u >> 16);
}
__device__ __forceinline__ float bf2f(unsigned short s) {
  return __uint_as_float(((unsigned)s) << 16);
}
__device__ __forceinline__ void gld_lds16(void* lds, const void* g) {
  __builtin_amdgcn_global_load_lds(
      (const __attribute__((address_space(1))) void*)g,
      (__attribute__((address_space(3))) void*)lds, 16, 0, 0);
}

// ws probe: if workspace too small, expose its MB count as d_out[0]
__global__ void ws_probe(float* out, float mb) { out[0] = mb; }

// ---------------- convert fp32 -> bf16 (vectorized) ----------------
__global__ __launch_bounds__(256) void cvt_bf16(const float* __restrict__ src,
                                                unsigned short* __restrict__ dst,
                                                size_t n4) {
  size_t i = (size_t)blockIdx.x * 256 + threadIdx.x;
  if (i < n4) {
    float4 v = ((const float4*)src)[i];
    ushort4 o;
    o.x = f2bf(v.x); o.y = f2bf(v.y); o.z = f2bf(v.z); o.w = f2bf(v.w);
    ((ushort4*)dst)[i] = o;
  }
}

// ---------------- exact fp32 GEMV for dt columns + fused x->bf16 ----------------
__global__ __launch_bounds__(256) void dt_gemv(const float* __restrict__ x,
                                               const float* __restrict__ W1,
                                               float* __restrict__ dtraw,
                                               unsigned short* __restrict__ xbf) {
  int row = blockIdx.x;
  __shared__ float xs[Ee];
  for (int i = threadIdx.x; i < Ee / 4; i += 256) {
    float4 v = ((const float4*)(x + (size_t)row * Ee))[i];
    ((float4*)xs)[i] = v;
    ushort4 o;
    o.x = f2bf(v.x); o.y = f2bf(v.y); o.z = f2bf(v.z); o.w = f2bf(v.w);
    ((ushort4*)(xbf + (size_t)row * Ee))[i] = o;
  }
  __syncthreads();
  int h = threadIdx.x >> 3, seg = threadIdx.x & 7;
  const float* wr = W1 + (size_t)(NG1 + h) * Ee;
  float s = 0.f;
  for (int k = seg; k < Ee; k += 8) s = fmaf(xs[k], wr[k], s);
  s += __shfl_xor(s, 1);
  s += __shfl_xor(s, 2);
  s += __shfl_xor(s, 4);
  if (seg == 0) dtraw[(size_t)row * Hh + h] = s;
}

// ---------------- bf16 MFMA GEMM, B given as N x K (B^T pattern) ----------------
// XOR-swizzled LDS (bank-conflict-free, verified r5) + 64x64 per-wave tiles
// (2x2 wave grid): 8 LDS frag reads per 16 MFMA instead of 10 — LDS-read-bound
// K-loop gets 1.25x more FLOP/LDS-byte.
// mode 0: plain fp32 out (pitch Nout).  mode 1: split epilogue gate/hbc (bf16).
#define BM 128
#define BN 128
#define BK 64
__global__ __launch_bounds__(256) void gemm_bt(const unsigned short* __restrict__ A,
                                               const unsigned short* __restrict__ B,
                                               int K, int mode,
                                               float* __restrict__ out_f,
                                               unsigned short* __restrict__ out_gate,
                                               unsigned short* __restrict__ out_hbc,
                                               int Nout) {
  __shared__ unsigned short As[BM * BK];
  __shared__ unsigned short Bs[BN * BK];
  const int tid = threadIdx.x;
  const int wid = tid >> 6, lane = tid & 63;
  const int q = lane >> 4, l16 = lane & 15;
  const int mw = (wid & 1) * 64, nw = (wid >> 1) * 64;
  const int m0 = blockIdx.y * BM;
  const int n0 = blockIdx.x * BN;
  floatx4 acc[4][4] = {};

  const int cb = tid & 192;  // wave-uniform chunk base bits (= wid*64)
  for (int k0 = 0; k0 < K; k0 += BK) {
    __syncthreads();
#pragma unroll
    for (int it = 0; it < 4; ++it) {
      int chunkbase = it * 256 + cb;
      int chunk = chunkbase + lane;
      int m = chunk >> 3;
      int k8d = (chunk & 7) ^ (m & 7);       // swizzled data octet
      gld_lds16(&As[chunkbase * 8], &A[(size_t)(m0 + m) * K + k0 + (k8d << 3)]);
      gld_lds16(&Bs[chunkbase * 8], &B[(size_t)(n0 + m) * K + k0 + (k8d << 3)]);
    }
    __syncthreads();
#pragma unroll
    for (int kk = 0; kk < BK; kk += 32) {
      const int k8 = (kk >> 3) + q;
      const int xo = ((k8 ^ (l16 & 7)) << 3);   // swizzled in-row offset (shorts)
      short8 af[4], bf[4];
#pragma unroll
      for (int mt = 0; mt < 4; ++mt)
        af[mt] = *(const short8*)&As[(mw + mt * 16 + l16) * BK + xo];
#pragma unroll
      for (int nt = 0; nt < 4; ++nt)
        bf[nt] = *(const short8*)&Bs[(nw + nt * 16 + l16) * BK + xo];
#pragma unroll
      for (int mt = 0; mt < 4; ++mt)
#pragma unroll
        for (int nt = 0; nt < 4; ++nt)
          acc[mt][nt] = __builtin_amdgcn_mfma_f32_16x16x32_bf16(af[mt], bf[nt], acc[mt][nt], 0, 0, 0);
    }
  }
#pragma unroll
  for (int mt = 0; mt < 4; ++mt)
#pragma unroll
    for (int nt = 0; nt < 4; ++nt)
#pragma unroll
      for (int r = 0; r < 4; ++r) {
        int row = m0 + mw + mt * 16 + q * 4 + r;
        int col = n0 + nw + nt * 16 + l16;
        float v = acc[mt][nt][r];
        if (mode == 0) {
          out_f[(size_t)row * Nout + col] = v;
        } else {
          if (col < Ii) out_gate[(size_t)row * Ii + col] = f2bf(v);
          else out_hbc[(size_t)row * CDd + (col - Ii)] = f2bf(v);
        }
      }
}

// ---------------- depthwise causal conv K=4 + bias + silu, split bf16 outputs ----------------
__global__ __launch_bounds__(256) void conv_silu(const unsigned short* __restrict__ hbc,
                                                 const float* __restrict__ cw,
                                                 const float* __restrict__ cb,
                                                 unsigned short* __restrict__ Xr,
                                                 unsigned short* __restrict__ Bb,
                                                 unsigned short* __restrict__ Cb) {
  int idx = blockIdx.x * 256 + threadIdx.x;   // over Mm*CDd/4
  int c4 = (idx % (CDd / 4)) * 4;
  int row = idx / (CDd / 4);
  int s = row & 2047;
  const unsigned short* base = hbc + (size_t)row * CDd + c4;
  ushort4 zero = {0, 0, 0, 0};
  ushort4 r0 = (s >= 3) ? *(const ushort4*)(base - (size_t)3 * CDd) : zero;
  ushort4 r1 = (s >= 2) ? *(const ushort4*)(base - (size_t)2 * CDd) : zero;
  ushort4 r2 = (s >= 1) ? *(const ushort4*)(base - (size_t)1 * CDd) : zero;
  ushort4 r3 = *(const ushort4*)base;
  float i0[4] = {bf2f(r0.x), bf2f(r0.y), bf2f(r0.z), bf2f(r0.w)};
  float i1[4] = {bf2f(r1.x), bf2f(r1.y), bf2f(r1.z), bf2f(r1.w)};
  float i2[4] = {bf2f(r2.x), bf2f(r2.y), bf2f(r2.z), bf2f(r2.w)};
  float i3[4] = {bf2f(r3.x), bf2f(r3.y), bf2f(r3.z), bf2f(r3.w)};
  ushort4 o;
  unsigned short* op = (unsigned short*)&o;
#pragma unroll
  for (int ch = 0; ch < 4; ++ch) {
    int c = c4 + ch;
    float4 w = *(const float4*)&cw[c * 4];
    float v = cb[c];
    v = fmaf(i0[ch], w.x, v);
    v = fmaf(i1[ch], w.y, v);
    v = fmaf(i2[ch], w.z, v);
    v = fmaf(i3[ch], w.w, v);
    v = v / (1.f + expf(-v));
    op[ch] = f2bf(v);
  }
  if (c4 < Ii) *(ushort4*)&Xr[(size_t)row * Ii + c4] = o;
  else if (c4 < Ii + GNn) *(ushort4*)&Bb[(size_t)row * GNn + (c4 - Ii)] = o;
  else *(ushort4*)&Cb[(size_t)row * GNn + (c4 - Ii - GNn)] = o;
}

// ---------------- softplus(dt)+bias, A*dt chunk cumsum ----------------
__global__ __launch_bounds__(256) void dt_cumsum(const float* __restrict__ dtraw,
                                                 const float* __restrict__ dt_bias,
                                                 const float* __restrict__ A_log,
                                                 float* __restrict__ dtbuf,
                                                 float* __restrict__ Acum) {
  int bc = blockIdx.x;   // b*8+c
  int h = blockIdx.y;
  int l = threadIdx.x;
  int row = bc * CHc + l;
  float xv = dtraw[(size_t)row * Hh + h] + dt_bias[h];
  float dt = (xv > 20.f) ? xv : log1pf(expf(xv));
  dtbuf[(size_t)row * Hh + h] = dt;
  float a = -expf(A_log[h]) * dt;
  __shared__ float buf[CHc];
  buf[l] = a;
  __syncthreads();
  for (int off = 1; off < CHc; off <<= 1) {
    float v = (l >= off) ? buf[l - off] : 0.f;
    __syncthreads();
    buf[l] += v;
    __syncthreads();
  }
  Acum[((size_t)bc * Hh + h) * CHc + l] = buf[l];
}

// ---------------- per-chunk states via MFMA (64x64 wave tiles) ----------------
// S_T[p][n] = sum_l (w[l]*X[l,p]) * B[l,n]  ([p][n] layout)
__global__ __launch_bounds__(256, 2) void states_kernel(const unsigned short* __restrict__ Xraw,
                                                        const unsigned short* __restrict__ Bbuf,
                                                        const float* __restrict__ dtbuf,
                                                        const float* __restrict__ Acum,
                                                        unsigned short* __restrict__ states) {
  int bch = blockIdx.x;            // (b*8+c)*32 + h
  int h = bch & 31, bc = bch >> 5;
  int g = h & 7;
  int rowbase = bc * CHc;
  const float* Ac = Acum + (size_t)bch * CHc;
  __shared__ unsigned short XTt[128 * 136];  // [p][l] weighted (A-op)
  __shared__ unsigned short BTt[128 * 136];  // [n][l] (B-op)
  __shared__ float wl[128];
  int t = threadIdx.x;
  int wid = t >> 6, lane = t & 63, q = lane >> 4, l16 = lane & 15;
  int mw = (wid & 1) * 64, nw = (wid >> 1) * 64;
  float Alast = Ac[CHc - 1];
  floatx4 acc[4][4] = {};
  for (int lt = 0; lt < 2; ++lt) {
    int l0 = lt * 128;
    if (t < 128)
      wl[t] = dtbuf[(size_t)(rowbase + l0 + t) * Hh + h] * __expf(Alast - Ac[l0 + t]);
    __syncthreads();
    for (int i = t; i < 2048; i += 256) {
      int r = i >> 4, c8 = (i & 15) * 8;
      int row = rowbase + l0 + r;
      const unsigned short* xp = &Xraw[(size_t)row * Ii + h * Pp + c8];
      const unsigned short* bp = &Bbuf[(size_t)row * GNn + g * Nn + c8];
      ushort4 xa = *(const ushort4*)xp;
      ushort4 xb = *(const ushort4*)(xp + 4);
      ushort4 ba = *(const ushort4*)bp;
      ushort4 bb = *(const ushort4*)(bp + 4);
      float w = wl[r];
      XTt[(c8 + 0) * 136 + r] = f2bf(bf2f(xa.x) * w);
      XTt[(c8 + 1) * 136 + r] = f2bf(bf2f(xa.y) * w);
      XTt[(c8 + 2) * 136 + r] = f2bf(bf2f(xa.z) * w);
      XTt[(c8 + 3) * 136 + r] = f2bf(bf2f(xa.w) * w);
      XTt[(c8 + 4) * 136 + r] = f2bf(bf2f(xb.x) * w);
      XTt[(c8 + 5) * 136 + r] = f2bf(bf2f(xb.y) * w);
      XTt[(c8 + 6) * 136 + r] = f2bf(bf2f(xb.z) * w);
      XTt[(c8 + 7) * 136 + r] = f2bf(bf2f(xb.w) * w);
      BTt[(c8 + 0) * 136 + r] = ba.x;
      BTt[(c8 + 1) * 136 + r] = ba.y;
      BTt[(c8 + 2) * 136 + r] = ba.z;
      BTt[(c8 + 3) * 136 + r] = ba.w;
      BTt[(c8 + 4) * 136 + r] = bb.x;
      BTt[(c8 + 5) * 136 + r] = bb.y;
      BTt[(c8 + 6) * 136 + r] = bb.z;
      BTt[(c8 + 7) * 136 + r] = bb.w;
    }
    __syncthreads();
#pragma unroll
    for (int kk = 0; kk < 128; kk += 32) {
      int ko = kk + q * 8;
      short8 af[4], bf[4];
#pragma unroll
      for (int mt = 0; mt < 4; ++mt)
        af[mt] = *(const short8*)&XTt[(mw + mt * 16 + l16) * 136 + ko];
#pragma unroll
      for (int nt = 0; nt < 4; ++nt)
        bf[nt] = *(const short8*)&BTt[(nw + nt * 16 + l16) * 136 + ko];
#pragma unroll
      for (int mt = 0; mt < 4; ++mt)
#pragma unroll
        for (int nt = 0; nt < 4; ++nt)
          acc[mt][nt] = __builtin_amdgcn_mfma_f32_16x16x32_bf16(af[mt], bf[nt], acc[mt][nt], 0, 0, 0);
    }
  }
  unsigned short* so = states + (size_t)bch * (Nn * Pp);
#pragma unroll
  for (int mt = 0; mt < 4; ++mt)
#pragma unroll
    for (int nt = 0; nt < 4; ++nt)
#pragma unroll
      for (int r = 0; r < 4; ++r)
        so[(size_t)(mw + mt * 16 + q * 4 + r) * Nn + nw + nt * 16 + l16] =
            f2bf(acc[mt][nt][r]);
}

// ---------------- sequential chunk recurrence -> states_prev ([p][n] layout) ----------------
__global__ __launch_bounds__(256) void chunk_scan(const unsigned short* __restrict__ states,
                                                  const float* __restrict__ Acum,
                                                  unsigned short* __restrict__ sprev) {
  int bh = blockIdx.x;  // b*32+h
  int b = bh >> 5, h = bh & 31;
  float dec[NCn];
#pragma unroll
  for (int c = 0; c < NCn; ++c)
    dec[c] = expf(Acum[((size_t)((b * NCn + c) * Hh + h)) * CHc + (CHc - 1)]);
  int e0 = blockIdx.y * 2048 + threadIdx.x;
  for (int e = e0; e < (int)(blockIdx.y + 1) * 2048; e += 256) {
    float S = 0.f;
#pragma unroll
    for (int c = 0; c < NCn; ++c) {
      size_t off = ((size_t)((b * NCn + c) * Hh + h)) * (Nn * Pp) + e;
      sprev[off] = f2bf(S);
      S = fmaf(dec[c], S, bf2f(states[off]));
    }
  }
}

// ---------------- Y = Y_diag + Y_off via MFMA, per (b,c,h,ltile128) ----------------
// 512 threads, 8 waves as 2(l) x 4(p/s) grid of 64x32 tiles; Gs aliases Bt.
#define YS 136
__global__ __launch_bounds__(512, 1) void y_kernel(const unsigned short* __restrict__ Xraw,
                                                   const unsigned short* __restrict__ Bbuf,
                                                   const unsigned short* __restrict__ Cbuf,
                                                   const float* __restrict__ dtbuf,
                                                   const float* __restrict__ Acum,
                                                   const unsigned short* __restrict__ sprev,
                                                   unsigned short* __restrict__ ybuf) {
  int bid = blockIdx.x;
  int lt = bid & 1;
  int bch = bid >> 1;
  int h = bch & 31, bc = bch >> 5;
  int g = h & 7;
  int rowbase = bc * CHc;
  int l0 = lt * 128;
  const float* Ac = Acum + (size_t)bch * CHc;

  __shared__ unsigned short Ct[128 * YS];   // [l][n]
  __shared__ unsigned short Bt[128 * YS];   // [s][n] GEMM1; Gs [l][s]; sprev [p][n]
  __shared__ unsigned short Xt[128 * YS];   // [p][s]
  __shared__ float Acl[128], Aex[128], Ast[128], dts[128];
  unsigned short* Gs = Bt;

  int t = threadIdx.x;
  int wid = t >> 6, lane = t & 63, q = lane >> 4, l16 = lane & 15;
  int lw = (wid & 1) * 64;      // l (m-dim) wave base
  int pw = (wid >> 1) * 32;     // p/s (n-dim) wave base

  for (int i = t; i < 2048; i += 512) {
    int r = i >> 4, c8 = (i & 15) * 8;
    *(uint4*)&Ct[r * YS + c8] =
        *(const uint4*)&Cbuf[(size_t)(rowbase + l0 + r) * GNn + g * Nn + c8];
  }
  if (t < 128) {
    float a = Ac[l0 + t];
    Acl[t] = a;
    Aex[t] = __expf(a);
  }

  floatx4 acc[4][2] = {};

  for (int st = 0; st <= lt; ++st) {
    int s0 = st * 128;
    __syncthreads();   // prior GEMM2 (reads Gs=Bt) done
    for (int i = t; i < 2048; i += 512) {
      int r = i >> 4, c8 = (i & 15) * 8;
      int row = rowbase + s0 + r;
      *(uint4*)&Bt[r * YS + c8] =
          *(const uint4*)&Bbuf[(size_t)row * GNn + g * Nn + c8];
      const unsigned short* xp = &Xraw[(size_t)row * Ii + h * Pp + c8];
      ushort4 xa = *(const ushort4*)xp;
      ushort4 xb = *(const ushort4*)(xp + 4);
      Xt[(c8 + 0) * YS + r] = xa.x;
      Xt[(c8 + 1) * YS + r] = xa.y;
      Xt[(c8 + 2) * YS + r] = xa.z;
      Xt[(c8 + 3) * YS + r] = xa.w;
      Xt[(c8 + 4) * YS + r] = xb.x;
      Xt[(c8 + 5) * YS + r] = xb.y;
      Xt[(c8 + 6) * YS + r] = xb.z;
      Xt[(c8 + 7) * YS + r] = xb.w;
    }
    if (t < 128) {
      Ast[t] = Ac[s0 + t];
      dts[t] = dtbuf[(size_t)(rowbase + s0 + t) * Hh + h];
    }
    __syncthreads();
    // GEMM1: G = C · B^T   (wave tile: l in [lw,lw+64), s in [pw,pw+32))
    floatx4 gacc[4][2] = {};
#pragma unroll
    for (int kk = 0; kk < 128; kk += 32) {
      int ko = kk + q * 8;
      short8 af[4], bf[2];
#pragma unroll
      for (int mt = 0; mt < 4; ++mt)
        af[mt] = *(const short8*)&Ct[(lw + mt * 16 + l16) * YS + ko];
#pragma unroll
      for (int nt = 0; nt < 2; ++nt)
        bf[nt] = *(const short8*)&Bt[(pw + nt * 16 + l16) * YS + ko];
#pragma unroll
      for (int mt = 0; mt < 4; ++mt)
#pragma unroll
        for (int nt = 0; nt < 2; ++nt)
          gacc[mt][nt] = __builtin_amdgcn_mfma_f32_16x16x32_bf16(af[mt], bf[nt], gacc[mt][nt], 0, 0, 0);
    }
    __syncthreads();   // all waves done reading Bt before Gs overwrite
    bool diag = (st == lt);
#pragma unroll
    for (int mt = 0; mt < 4; ++mt)
#pragma unroll
      for (int nt = 0; nt < 2; ++nt)
#pragma unroll
        for (int r = 0; r < 4; ++r) {
          int l_loc = lw + mt * 16 + q * 4 + r;
          int s_loc = pw + nt * 16 + l16;
          float v = gacc[mt][nt][r] * dts[s_loc] * __expf(Acl[l_loc] - Ast[s_loc]);
          Gs[l_loc * YS + s_loc] = (!diag || s_loc <= l_loc) ? f2bf(v) : (unsigned short)0;
        }
    __syncthreads();
    // GEMM2: Y += G · X   (A = Gs [l][s], B-op = Xt [p][s]; wave: l 64 x p 32)
#pragma unroll
    for (int kk = 0; kk < 128; kk += 32) {
      int ko = kk + q * 8;
      short8 af[4], bf[2];
#pragma unroll
      for (int mt = 0; mt < 4; ++mt)
        af[mt] = *(const short8*)&Gs[(lw + mt * 16 + l16) * YS + ko];
#pragma unroll
      for (int nt = 0; nt < 2; ++nt)
        bf[nt] = *(const short8*)&Xt[(pw + nt * 16 + l16) * YS + ko];
#pragma unroll
      for (int mt = 0; mt < 4; ++mt)
#pragma unroll
        for (int nt = 0; nt < 2; ++nt)
          acc[mt][nt] = __builtin_amdgcn_mfma_f32_16x16x32_bf16(af[mt], bf[nt], acc[mt][nt], 0, 0, 0);
    }
  }
  __syncthreads();   // last GEMM2 done before overwriting Bt(=Gs) with sprev
  // scale Ct rows by exp(Acum[l]); stage sprev [p][n] into Bt
  for (int i = t; i < 2048; i += 512) {
    int r = i >> 4, c8 = (i & 15) * 8;
    uint4 cv = *(uint4*)&Ct[r * YS + c8];
    unsigned short* cp = (unsigned short*)&cv;
    float e = Aex[r];
#pragma unroll
    for (int j = 0; j < 8; ++j) cp[j] = f2bf(bf2f(cp[j]) * e);
    *(uint4*)&Ct[r * YS + c8] = cv;
    *(uint4*)&Bt[r * YS + c8] =
        *(const uint4*)&sprev[(size_t)bch * (Nn * Pp) + (size_t)i * 8];
  }
  __syncthreads();
  // Y_off: Y += C~ · Sprev   (A = scaled Ct [l][n], B-op = Bt [p][n])
#pragma unroll
  for (int kk = 0; kk < 128; kk += 32) {
    int ko = kk + q * 8;
    short8 af[4], bf[2];
#pragma unroll
    for (int mt = 0; mt < 4; ++mt)
      af[mt] = *(const short8*)&Ct[(lw + mt * 16 + l16) * YS + ko];
#pragma unroll
    for (int nt = 0; nt < 2; ++nt)
      bf[nt] = *(const short8*)&Bt[(pw + nt * 16 + l16) * YS + ko];
#pragma unroll
    for (int mt = 0; mt < 4; ++mt)
#pragma unroll
      for (int nt = 0; nt < 2; ++nt)
        acc[mt][nt] = __builtin_amdgcn_mfma_f32_16x16x32_bf16(af[mt], bf[nt], acc[mt][nt], 0, 0, 0);
  }
  // epilogue: Y_diag + Y_off (D*X added in norm_kernel)
#pragma unroll
  for (int mt = 0; mt < 4; ++mt)
#pragma unroll
    for (int nt = 0; nt < 2; ++nt)
#pragma unroll
      for (int r = 0; r < 4; ++r) {
        int row = rowbase + l0 + lw + mt * 16 + q * 4 + r;
        int col = h * Pp + pw + nt * 16 + l16;
        ybuf[(size_t)row * Ii + col] = f2bf(acc[mt][nt][r]);
      }
}

// ---------------- gated group RMSNorm (adds D*X) -> bf16 ----------------
// NOTE: xraw and normed alias — each element read-before-write by its own thread.
__global__ __launch_bounds__(256) void norm_kernel(const unsigned short* ybuf,
                                                   const unsigned short* gate_bf,
                                                   const unsigned short* xraw,
                                                   const float* Dvec,
                                                   const float* norm_w,
                                                   unsigned short* normed) {
  int blk = blockIdx.x;  // row*8 + grp
  int row = blk >> 3, grp = blk & 7;
  size_t base = (size_t)row * Ii + grp * 512;
  int t = threadIdx.x;
  int col0 = grp * 512 + t, col1 = col0 + 256;
  float D0 = Dvec[col0 >> 7], D1 = Dvec[col1 >> 7];
  float y0 = bf2f(ybuf[base + t]) + D0 * bf2f(xraw[base + t]);
  float y1 = bf2f(ybuf[base + t + 256]) + D1 * bf2f(xraw[base + t + 256]);
  float g0 = bf2f(gate_bf[base + t]), g1 = bf2f(gate_bf[base + t + 256]);
  float h0 = y0 * (g0 / (1.f + expf(-g0)));
  float h1 = y1 * (g1 / (1.f + expf(-g1)));
  __shared__ float red[256];
  red[t] = h0 * h0 + h1 * h1;
  __syncthreads();
  for (int off = 128; off > 0; off >>= 1) {
    if (t < off) red[t] += red[t + off];
    __syncthreads();
  }
  float scale = rsqrtf(red[0] / 512.f + 1e-6f);
  normed[base + t] = f2bf(h0 * scale * norm_w[grp * 512 + t]);
  normed[base + t + 256] = f2bf(h1 * scale * norm_w[grp * 512 + t + 256]);
}

extern "C" void kernel_launch(void* const* d_in, const int* in_sizes, int n_in,
                              void* d_out, int out_size, void* d_ws, size_t ws_size,
                              hipStream_t stream) {
  const float* x    = (const float*)d_in[0];
  const float* W1   = (const float*)d_in[1];
  const float* cw   = (const float*)d_in[2];
  const float* cb   = (const float*)d_in[3];
  const float* dtb  = (const float*)d_in[4];
  const float* Alog = (const float*)d_in[5];
  const float* Dv   = (const float*)d_in[6];
  const float* nw   = (const float*)d_in[7];
  const float* W2   = (const float*)d_in[8];
  float* out = (float*)d_out;
  char* ws = (char*)d_ws;

  // ws layout (bytes), total ~185.5 MiB (known-good).
  const size_t o_xbf   = 0;                        // 16,777,216
  const size_t o_w1    = 16777216ull;              // 41,943,040
  const size_t o_gate  = o_w1 + 41943040ull;       // 33,554,432
  const size_t o_hbc   = o_gate + 33554432ull;     // 50,331,648
  const size_t o_xraw  = o_hbc + 50331648ull;      // 33,554,432
  const size_t o_b     = o_xraw + 33554432ull;     // 8,388,608
  const size_t o_c     = o_b + 8388608ull;         // 8,388,608
  const size_t o_dtraw = o_c + 8388608ull;         // 524,288
  const size_t o_dt    = o_dtraw + 524288ull;      // 524,288
  const size_t o_acum  = o_dt + 524288ull;         // 524,288
  const size_t total   = o_acum + 524288ull;       // 194,510,848
  if (ws_size < total) {
    ws_probe<<<1, 1, 0, stream>>>(out, (float)(ws_size >> 20));
    return;
  }

  unsigned short* xbf    = (unsigned short*)(ws + o_xbf);
  unsigned short* w1bf   = (unsigned short*)(ws + o_w1);
  unsigned short* states = (unsigned short*)(ws + o_w1);               // alias
  unsigned short* sprev  = (unsigned short*)(ws + o_w1 + 16777216ull); // alias
  unsigned short* w2bf   = (unsigned short*)(ws + o_w1);               // alias (late)
  unsigned short* gatebf = (unsigned short*)(ws + o_gate);
  unsigned short* hbc    = (unsigned short*)(ws + o_hbc);
  unsigned short* ybuf   = (unsigned short*)(ws + o_hbc);              // alias
  unsigned short* xraw   = (unsigned short*)(ws + o_xraw);
  unsigned short* normed = (unsigned short*)(ws + o_xraw);             // alias (late)
  unsigned short* bbuf   = (unsigned short*)(ws + o_b);
  unsigned short* cbuf   = (unsigned short*)(ws + o_c);
  float* dtraw  = (float*)(ws + o_dtraw);
  float* dtbuf  = (float*)(ws + o_dt);
  float* acum   = (float*)(ws + o_acum);

  // 1. W1 convert (x convert fused into dt_gemv)
  cvt_bf16<<<dim3(20480), dim3(256), 0, stream>>>(W1, w1bf, (size_t)5242880);
  // 2. exact dt columns (fp32) + x->bf16
  dt_gemv<<<dim3(Mm), dim3(256), 0, stream>>>(x, W1, dtraw, xbf);
  // 3. GEMM1 -> gate(bf16) + hbc(bf16)
  gemm_bt<<<dim3(NG1 / BN, Mm / BM), dim3(256), 0, stream>>>(
      xbf, w1bf, Ee, 1, nullptr, gatebf, hbc, 0);
  // 4. conv + silu -> X, B, C (bf16)
  conv_silu<<<dim3((Mm * CDd / 4) / 256), dim3(256), 0, stream>>>(hbc, cw, cb, xraw, bbuf, cbuf);
  // 5. dt softplus + A*dt cumsum
  dt_cumsum<<<dim3(16, Hh), dim3(CHc), 0, stream>>>(dtraw, dtb, Alog, dtbuf, acum);
  // 6. per-chunk states (MFMA, [p][n]; overwrites w1bf — GEMM1 done)
  states_kernel<<<dim3(512), dim3(256), 0, stream>>>(xraw, bbuf, dtbuf, acum, states);
  // 7. chunk recurrence
  chunk_scan<<<dim3(64, 8), dim3(256), 0, stream>>>(states, acum, sprev);
  // 8. convert W2 into states' slot (states dead; sprev untouched)
  cvt_bf16<<<dim3(8192), dim3(256), 0, stream>>>(W2, w2bf, (size_t)2097152);
  // 9. Y (MFMA, 512 threads)
  y_kernel<<<dim3(1024), dim3(512), 0, stream>>>(xraw, bbuf, cbuf, dtbuf, acum, sprev, ybuf);
  // 10. gated RMSNorm (+ D*X) -> bf16 (normed overwrites xraw after read)
  norm_kernel<<<dim3(Mm * 8), dim3(256), 0, stream>>>(ybuf, gatebf, xraw, Dv, nw, normed);
  // 11. GEMM2 -> out (fp32)
  gemm_bt<<<dim3(Ee / BN, Mm / BM), dim3(256), 0, stream>>>(
      normed, w2bf, Ii, 0, out, nullptr, nullptr, Ee);
}